// Round 2
// baseline (535.403 us; speedup 1.0000x reference)
//
#include <hip/hip_runtime.h>
#include <stdint.h>
#include <math.h>

#define N_ROWS 16384
#define D_DIM  4096
#define E_EXP  128
#define BM     64                 // rows per block = lanes per wave
#define BK     64                 // k per tile
#define NT     (D_DIM / BK)       // 64 tiles
#define EW     16                 // experts per wave
#define NWAVE  8                  // 8 waves * 16 experts = 128

#define GAS __attribute__((address_space(1)))
#define LAS __attribute__((address_space(3)))

__device__ __forceinline__ void g2lds16(const float* g, float* l) {
  __builtin_amdgcn_global_load_lds((const GAS uint32_t*)g, (LAS uint32_t*)l, 16, 0, 0);
}

// strict total order: conf desc, then logit desc, then index asc  (same as R1 pass)
__device__ __forceinline__ bool cand_gt(float ca, double la, int ia,
                                        float cb, double lb, int ib) {
  if (ca != cb) return ca > cb;
  if (la != lb) return la > lb;
  return ia < ib;
}

struct Top2 { float c0, c1; double l0, l1; int i0, i1; };

__device__ __forceinline__ void top2_ins(Top2& s, float c, double l, int i) {
  if (cand_gt(c, l, i, s.c0, s.l0, s.i0)) {
    s.c1 = s.c0; s.l1 = s.l0; s.i1 = s.i0;
    s.c0 = c;    s.l0 = l;    s.i0 = i;
  } else if (cand_gt(c, l, i, s.c1, s.l1, s.i1)) {
    s.c1 = c;    s.l1 = l;    s.i1 = i;
  }
}

__global__ __launch_bounds__(512) void gate_kernel(
    const float* __restrict__ x, const float* __restrict__ Wm,
    const float* __restrict__ bias, float* __restrict__ out)
{
  // LDS: Xs[2][64 rows][64 k] f32 = 32 KiB (XOR-swizzled 16B granules)
  __shared__ __align__(16) uint8_t smem[32768];
  float* Xs = (float*)smem;
  // epilogue overlay (used only after the loop's final barrier):
  float*  Rc = (float*)smem;            // [8][64][2] f32   4 KiB
  double* Rl = (double*)(smem + 4096);  // [8][64][2] f64   8 KiB
  int*    Ri = (int*)(smem + 12288);    // [8][64][2] i32   4 KiB

  const int t    = threadIdx.x;
  const int lane = t & 63;
  const int wv   = __builtin_amdgcn_readfirstlane((int)(threadIdx.x >> 6));
  const int row0 = blockIdx.x * BM;
  const int l7   = lane & 7;
  const int xfb  = lane * BK;           // float offset of this lane's row

  // ---- staging map: slot p of row r holds source granule (p ^ (r&7)) ----
  // thread t stages granule c1 = t (rows 0..31) and c2 = 512+t (rows 32..63)
  const int sr = t >> 4;                // 0..31
  const int sp = t & 15;
  const int sg = sp ^ (sr & 7);
  const float* xsrc = x + (size_t)(row0 + sr) * D_DIM + sg * 4;

  const float* Wbase = Wm + (size_t)(wv * EW) * D_DIM;  // uniform per wave

  float  acc[EW];
  double acc64[EW];
  #pragma unroll
  for (int j = 0; j < EW; ++j) acc64[j] = 0.0;

  auto stage = [&](int buf, int kt) {
    const float* s = xsrc + kt * BK;
    float* db = Xs + buf * 4096;
    g2lds16(s, db + t * 4);
    g2lds16(s + (size_t)32 * D_DIM, db + 2048 + t * 4);
  };

  stage(0, 0);
  __syncthreads();

  for (int kt = 0; kt < NT; ++kt) {
    if (kt + 1 < NT) stage((kt + 1) & 1, kt + 1);
    const float* Xb = Xs + (kt & 1) * 4096;
    const float* Wk = Wbase + kt * BK;

    #pragma unroll
    for (int half = 0; half < 2; ++half) {
      #pragma unroll
      for (int j = 0; j < EW; ++j) acc[j] = 0.f;
      #pragma unroll
      for (int gg = 0; gg < 8; ++gg) {
        const int g = half * 8 + gg;
        float4 xv = *(const float4*)(Xb + xfb + ((g ^ l7) << 2));
        #pragma unroll
        for (int j = 0; j < EW; ++j) {
          float4 w4 = *(const float4*)(Wk + (size_t)j * D_DIM + g * 4);
          acc[j] = fmaf(xv.w, w4.w,
                   fmaf(xv.z, w4.z,
                   fmaf(xv.y, w4.y,
                   fmaf(xv.x, w4.x, acc[j]))));
        }
      }
      #pragma unroll
      for (int j = 0; j < EW; ++j) acc64[j] += (double)acc[j];  // fold every 32 k
    }
    __syncthreads();
  }

  // ---- epilogue: bias + f64 sigmoid + per-lane top2 over this wave's 16 experts
  Top2 s;
  s.c0 = s.c1 = -1.0f; s.l0 = s.l1 = -1.0e300; s.i0 = s.i1 = 0x7fffffff;
  #pragma unroll
  for (int j = 0; j < EW; ++j) {
    int e = wv * EW + j;
    double lg = acc64[j] + (double)bias[e];
    float cf = (float)(1.0 / (1.0 + exp(-lg)));
    top2_ins(s, cf, lg, e);
  }
  {
    int ridx = (wv * 64 + lane) * 2;
    Rc[ridx + 0] = s.c0; Rc[ridx + 1] = s.c1;
    Rl[ridx + 0] = s.l0; Rl[ridx + 1] = s.l1;
    Ri[ridx + 0] = s.i0; Ri[ridx + 1] = s.i1;
  }
  __syncthreads();

  // ---- cross-wave merge: thread t<64 merges 8 waves' top2 for row t ----
  if (t < 64) {
    Top2 m;
    m.c0 = m.c1 = -1.0f; m.l0 = m.l1 = -1.0e300; m.i0 = m.i1 = 0x7fffffff;
    #pragma unroll
    for (int w = 0; w < NWAVE; ++w) {
      int ei = (w * 64 + t) * 2;
      top2_ins(m, Rc[ei + 0], Rl[ei + 0], Ri[ei + 0]);
      top2_ins(m, Rc[ei + 1], Rl[ei + 1], Ri[ei + 1]);
    }
    int grow = row0 + t;
    out[(size_t)grow * 2 + 0] = m.c0;
    out[(size_t)grow * 2 + 1] = m.c1;
    out[(size_t)N_ROWS * 2 + (size_t)grow * 2 + 0] = (float)m.i0;
    out[(size_t)N_ROWS * 2 + (size_t)grow * 2 + 1] = (float)m.i1;
  }
}

extern "C" void kernel_launch(void* const* d_in, const int* in_sizes, int n_in,
                              void* d_out, int out_size, void* d_ws, size_t ws_size,
                              hipStream_t stream) {
  const float* x  = (const float*)d_in[0];
  const float* Wm = (const float*)d_in[1];
  const float* b  = (const float*)d_in[2];
  float* out = (float*)d_out;
  dim3 grid(N_ROWS / BM);   // 256 blocks x 512 threads
  dim3 block(512);
  gate_kernel<<<grid, block, 0, stream>>>(x, Wm, b, out);
}

// Round 4
// 468.484 us; speedup vs baseline: 1.1428x; 1.1428x over previous
//
#include <hip/hip_runtime.h>
#include <stdint.h>
#include <math.h>

#define N_ROWS 16384
#define D_DIM  4096
#define E_EXP  128
#define BM     32
#define BKT    64
#define NIT    (D_DIM / BKT)   // 64
#define TAU    2.5e-4f

typedef short  short8 __attribute__((ext_vector_type(8)));
typedef float  f32x4  __attribute__((ext_vector_type(4)));

__device__ __forceinline__ uint32_t bf16_rne(float f) {
  uint32_t u = __builtin_bit_cast(uint32_t, f);
  return (u + 0x7fffu + ((u >> 16) & 1u)) >> 16;
}

// ---------------- kernel 0: split W into bf16 hi/lo ----------------
__global__ __launch_bounds__(256) void k0_split(const float* __restrict__ W,
                                                uint16_t* __restrict__ wh,
                                                uint16_t* __restrict__ wl) {
  int i = (blockIdx.x * 256 + threadIdx.x) * 4;
  f32x4 w = *(const f32x4*)(W + i);
  uint32_t h[4], l[4];
  #pragma unroll
  for (int j = 0; j < 4; ++j) {
    h[j] = bf16_rne(w[j]);
    float hf = __builtin_bit_cast(float, h[j] << 16);
    l[j] = bf16_rne(w[j] - hf);
  }
  *(uint2*)(wh + i) = make_uint2(h[0] | (h[1] << 16), h[2] | (h[3] << 16));
  *(uint2*)(wl + i) = make_uint2(l[0] | (l[1] << 16), l[2] | (l[3] << 16));
}

// ---------------- kernel 1: main split-bf16 MFMA GEMM + top3 + flags ----------------
__global__ __launch_bounds__(256) void k1_main(
    const float* __restrict__ x, const uint16_t* __restrict__ wh,
    const uint16_t* __restrict__ wl, const float* __restrict__ bias,
    float* __restrict__ out, int* __restrict__ flags)
{
  __shared__ __align__(16) uint8_t smem[16384];   // 2 x 8KB staging; 16KB logits overlay
  float* Ld = (float*)smem;

  const int t    = threadIdx.x;
  const int lane = t & 63;
  const int wv   = __builtin_amdgcn_readfirstlane(t >> 6);  // wave -> experts [wv*32, wv*32+32)
  const int row0 = blockIdx.x * BM;

  // ---- X load map: thread t loads x[row0 + (t>>3)][kt*64 + (t&7)*8 .. +7] ----
  const int lr = t >> 3;          // 0..31
  const int lg = t & 7;           // k-group of 8 within 64
  const float* xp = x + (size_t)(row0 + lr) * D_DIM + lg * 8;

  // ---- LDS write map (pre-swizzled fragment layout) ----
  // frag block fb = s*4 + rg*2 + d (1KB each); 16B-slot p = gg*16 + (rr ^ (gg<<1) ^ s)
  const int s_w = lg >> 2, gg_w = lg & 3, rr_w = lr & 15, rg_w = lr >> 4;
  const int p_w  = gg_w * 16 + (rr_w ^ (gg_w << 1) ^ s_w);
  const int wa_h = (s_w * 4 + rg_w * 2 + 0) * 1024 + p_w * 16;
  const int wa_l = wa_h + 1024;

  // ---- LDS read map: frag(rg,s,d), lane: ggr=lane>>4, rrr=lane&15 ----
  const int ggr = lane >> 4, rrr = lane & 15;
  const int p_r0 = ggr * 16 + (rrr ^ (ggr << 1));   // s=0 ; s=1 is p_r0^1

  // ---- B (W) global fragment map: lane holds W[e0+ef*16+(lane&15)][k0+(lane>>4)*8 ..+7]
  const int ccol = lane & 15, gB = lane >> 4;
  const size_t erow0 = (size_t)(wv * 32 + ccol) * D_DIM;
  const size_t erow1 = (size_t)(wv * 32 + 16 + ccol) * D_DIM;

  f32x4 acc[2][2] = {};

  f32x4 x0, x1;
  x0 = __builtin_nontemporal_load((const f32x4*)xp);
  x1 = __builtin_nontemporal_load((const f32x4*)xp + 1);

  #pragma unroll 1
  for (int kt = 0; kt < NIT; ++kt) {
    // convert staged f32 -> bf16 h/l, write to LDS buf[kt&1]
    float xf[8] = {x0[0], x0[1], x0[2], x0[3], x1[0], x1[1], x1[2], x1[3]};
    uint32_t hpk[4], lpk[4];
    #pragma unroll
    for (int j = 0; j < 4; ++j) {
      uint32_t h0 = bf16_rne(xf[2*j]), h1 = bf16_rne(xf[2*j+1]);
      float h0f = __builtin_bit_cast(float, h0 << 16);
      float h1f = __builtin_bit_cast(float, h1 << 16);
      uint32_t l0 = bf16_rne(xf[2*j] - h0f), l1 = bf16_rne(xf[2*j+1] - h1f);
      hpk[j] = h0 | (h1 << 16);
      lpk[j] = l0 | (l1 << 16);
    }
    uint8_t* buf = smem + (kt & 1) * 8192;
    *(uint4*)(buf + wa_h) = make_uint4(hpk[0], hpk[1], hpk[2], hpk[3]);
    *(uint4*)(buf + wa_l) = make_uint4(lpk[0], lpk[1], lpk[2], lpk[3]);

    // prefetch next X tile into regs (stays in flight across the barrier)
    if (kt + 1 < NIT) {
      const f32x4* np = (const f32x4*)(xp + (size_t)(kt + 1) * BKT);
      x0 = __builtin_nontemporal_load(np);
      x1 = __builtin_nontemporal_load(np + 1);
    }

    asm volatile("s_waitcnt lgkmcnt(0)" ::: "memory");
    __builtin_amdgcn_s_barrier();

    // compute tile kt
    #pragma unroll
    for (int s = 0; s < 2; ++s) {
      const size_t kofs = (size_t)kt * BKT + s * 32 + gB * 8;
      short8 bh0 = *(const short8*)(wh + erow0 + kofs);
      short8 bh1 = *(const short8*)(wh + erow1 + kofs);
      short8 bl0 = *(const short8*)(wl + erow0 + kofs);
      short8 bl1 = *(const short8*)(wl + erow1 + kofs);
      const int pr = p_r0 ^ s;
      #pragma unroll
      for (int rg = 0; rg < 2; ++rg) {
        const uint8_t* fb = buf + (s * 4 + rg * 2) * 1024 + pr * 16;
        short8 ah = *(const short8*)fb;
        short8 al = *(const short8*)(fb + 1024);
        acc[rg][0] = __builtin_amdgcn_mfma_f32_16x16x32_bf16(ah, bh0, acc[rg][0], 0, 0, 0);
        acc[rg][0] = __builtin_amdgcn_mfma_f32_16x16x32_bf16(al, bh0, acc[rg][0], 0, 0, 0);
        acc[rg][0] = __builtin_amdgcn_mfma_f32_16x16x32_bf16(ah, bl0, acc[rg][0], 0, 0, 0);
        acc[rg][1] = __builtin_amdgcn_mfma_f32_16x16x32_bf16(ah, bh1, acc[rg][1], 0, 0, 0);
        acc[rg][1] = __builtin_amdgcn_mfma_f32_16x16x32_bf16(al, bh1, acc[rg][1], 0, 0, 0);
        acc[rg][1] = __builtin_amdgcn_mfma_f32_16x16x32_bf16(ah, bl1, acc[rg][1], 0, 0, 0);
      }
    }
  }

  // ---- epilogue: logits -> LDS [32][128] ----
  float b0 = bias[wv * 32 + ccol];
  float b1 = bias[wv * 32 + 16 + ccol];
  __syncthreads();
  #pragma unroll
  for (int rg = 0; rg < 2; ++rg)
    #pragma unroll
    for (int ef = 0; ef < 2; ++ef)
      #pragma unroll
      for (int i = 0; i < 4; ++i) {
        int row = rg * 16 + ggr * 4 + i;
        int e = wv * 32 + ef * 16 + ccol;
        Ld[row * 128 + e] = acc[rg][ef][i] + (ef ? b1 : b0);
      }
  __syncthreads();

  // ---- top-3 per row: 8 threads/row, 16 logits each, then shfl merge ----
  {
    const int row = t >> 3, part = t & 7;
    float l1 = -3e38f, l2 = -3e38f, l3 = -3e38f;
    int   i1 = -1, i2 = -1, i3 = -1;
    auto ins = [&](float v, int e) {
      if (v > l1 || (v == l1 && e < i1)) { l3=l2; i3=i2; l2=l1; i2=i1; l1=v; i1=e; }
      else if (v > l2 || (v == l2 && e < i2)) { l3=l2; i3=i2; l2=v; i2=e; }
      else if (v > l3 || (v == l3 && e < i3)) { l3=v; i3=e; }
    };
    #pragma unroll
    for (int jj = 0; jj < 4; ++jj) {
      int j = (jj + t) & 3;                       // rotate to spread LDS banks
      const float* pp = Ld + row * 128 + part * 16 + j * 4;
      f32x4 v = *(const f32x4*)pp;
      int eb = part * 16 + j * 4;
      ins(v[0], eb); ins(v[1], eb + 1); ins(v[2], eb + 2); ins(v[3], eb + 3);
    }
    #pragma unroll
    for (int m = 1; m <= 4; m <<= 1) {
      float a1 = __shfl_xor(l1, m), a2 = __shfl_xor(l2, m), a3 = __shfl_xor(l3, m);
      int   b1i = __shfl_xor(i1, m), b2i = __shfl_xor(i2, m), b3i = __shfl_xor(i3, m);
      ins(a1, b1i); ins(a2, b2i); ins(a3, b3i);
    }
    if (part == 0) {
      int grow = row0 + row;
      int fl = ((l1 - l2) < TAU) || ((l2 - l3) < TAU);
      flags[grow] = fl;
      out[(size_t)grow * 2 + 0] = 1.f / (1.f + __expf(-l1));
      out[(size_t)grow * 2 + 1] = 1.f / (1.f + __expf(-l2));
      out[(size_t)N_ROWS * 2 + (size_t)grow * 2 + 0] = (float)i1;
      out[(size_t)N_ROWS * 2 + (size_t)grow * 2 + 1] = (float)i2;
    }
  }
}

// ---------------- kernel 2: exact f64 fixup for flagged rows ----------------
__global__ __launch_bounds__(256) void k2_fix(
    const float* __restrict__ x, const float* __restrict__ W,
    const float* __restrict__ bias, const int* __restrict__ flags,
    float* __restrict__ out)
{
  __shared__ double lgs[E_EXP];
  const int t = threadIdx.x;
  const int e = t >> 1, half = t & 1;
  const int rbase = blockIdx.x * 8;
  for (int rr = 0; rr < 8; ++rr) {
    const int row = rbase + rr;
    if (!flags[row]) continue;
    const f32x4* xp = (const f32x4*)(x + (size_t)row * D_DIM + half * 2048);
    const f32x4* wp = (const f32x4*)(W + (size_t)e * D_DIM + half * 2048);
    double acc = 0.0;
    for (int j = 0; j < 512; ++j) {
      f32x4 xv = xp[j], wv = wp[j];
      acc += (double)xv[0] * wv[0];
      acc += (double)xv[1] * wv[1];
      acc += (double)xv[2] * wv[2];
      acc += (double)xv[3] * wv[3];
    }
    double other = __shfl_xor(acc, 1);
    if (half == 0) lgs[e] = acc + other + (double)bias[e];
    __syncthreads();
    if (t == 0) {
      double l1 = -1e300, l2 = -1e300; int i1 = -1, i2 = -1;
      for (int ee = 0; ee < E_EXP; ++ee) {
        double v = lgs[ee];
        if (v > l1) { l2 = l1; i2 = i1; l1 = v; i1 = ee; }
        else if (v > l2) { l2 = v; i2 = ee; }
      }
      out[(size_t)row * 2 + 0] = (float)(1.0 / (1.0 + exp(-l1)));
      out[(size_t)row * 2 + 1] = (float)(1.0 / (1.0 + exp(-l2)));
      out[(size_t)N_ROWS * 2 + (size_t)row * 2 + 0] = (float)i1;
      out[(size_t)N_ROWS * 2 + (size_t)row * 2 + 1] = (float)i2;
    }
    __syncthreads();
  }
}

extern "C" void kernel_launch(void* const* d_in, const int* in_sizes, int n_in,
                              void* d_out, int out_size, void* d_ws, size_t ws_size,
                              hipStream_t stream) {
  const float* x  = (const float*)d_in[0];
  const float* Wm = (const float*)d_in[1];
  const float* b  = (const float*)d_in[2];
  float* out = (float*)d_out;

  uint16_t* wh = (uint16_t*)d_ws;                          // 1 MiB
  uint16_t* wl = wh + (size_t)E_EXP * D_DIM;               // 1 MiB
  int* flags = (int*)((uint8_t*)d_ws + 2u * 1024 * 1024);  // 64 KiB

  k0_split<<<dim3((E_EXP * D_DIM) / 1024), dim3(256), 0, stream>>>(Wm, wh, wl);
  k1_main<<<dim3(N_ROWS / BM), dim3(256), 0, stream>>>(x, wh, wl, b, out, flags);
  k2_fix<<<dim3(N_ROWS / 8), dim3(256), 0, stream>>>(x, Wm, b, flags, out);
}

// Round 5
// 234.398 us; speedup vs baseline: 2.2842x; 1.9987x over previous
//
#include <hip/hip_runtime.h>
#include <stdint.h>
#include <math.h>

#define N_ROWS 16384
#define D_DIM  4096
#define E_EXP  128
#define BM     32
#define BKT    64
#define NIT    (D_DIM / BKT)   // 64
#define TAU    2.5e-4f

typedef short  short8 __attribute__((ext_vector_type(8)));
typedef float  f32x4  __attribute__((ext_vector_type(4)));

__device__ __forceinline__ uint32_t bf16_rne(float f) {
  uint32_t u = __builtin_bit_cast(uint32_t, f);
  return (u + 0x7fffu + ((u >> 16) & 1u)) >> 16;
}

// ---------------- kernel 0: split W into bf16 hi/lo ----------------
__global__ __launch_bounds__(256) void k0_split(const float* __restrict__ W,
                                                uint16_t* __restrict__ wh,
                                                uint16_t* __restrict__ wl) {
  int i = (blockIdx.x * 256 + threadIdx.x) * 4;
  f32x4 w = *(const f32x4*)(W + i);
  uint32_t h[4], l[4];
  #pragma unroll
  for (int j = 0; j < 4; ++j) {
    h[j] = bf16_rne(w[j]);
    float hf = __builtin_bit_cast(float, h[j] << 16);
    l[j] = bf16_rne(w[j] - hf);
  }
  *(uint2*)(wh + i) = make_uint2(h[0] | (h[1] << 16), h[2] | (h[3] << 16));
  *(uint2*)(wl + i) = make_uint2(l[0] | (l[1] << 16), l[2] | (l[3] << 16));
}

// ---------------- kernel 1: main split-bf16 MFMA GEMM + top3 + flags ----------------
__global__ __launch_bounds__(256) void k1_main(
    const float* __restrict__ x, const uint16_t* __restrict__ wh,
    const uint16_t* __restrict__ wl, const float* __restrict__ bias,
    float* __restrict__ out, int* __restrict__ flags)
{
  __shared__ __align__(16) uint8_t smem[16384];   // 2 x 8KB staging; 16KB logits overlay
  float* Ld = (float*)smem;

  const int t    = threadIdx.x;
  const int lane = t & 63;
  const int wv   = __builtin_amdgcn_readfirstlane(t >> 6);  // wave -> experts [wv*32, wv*32+32)
  const int row0 = blockIdx.x * BM;

  // ---- X load map: thread t loads x[row0 + (t>>3)][kt*64 + (t&7)*8 .. +7] ----
  const int lr = t >> 3;          // 0..31
  const int lg = t & 7;           // k-group of 8 within 64
  const float* xp = x + (size_t)(row0 + lr) * D_DIM + lg * 8;

  // ---- LDS write map (pre-swizzled fragment layout) ----
  const int s_w = lg >> 2, gg_w = lg & 3, rr_w = lr & 15, rg_w = lr >> 4;
  const int p_w  = gg_w * 16 + (rr_w ^ (gg_w << 1) ^ s_w);
  const int wa_h = (s_w * 4 + rg_w * 2 + 0) * 1024 + p_w * 16;
  const int wa_l = wa_h + 1024;

  // ---- LDS read map ----
  const int ggr = lane >> 4, rrr = lane & 15;
  const int p_r0 = ggr * 16 + (rrr ^ (ggr << 1));   // s=0 ; s=1 is p_r0^1

  // ---- B (W) global fragment map ----
  const int ccol = lane & 15, gB = lane >> 4;
  const size_t erow0 = (size_t)(wv * 32 + ccol) * D_DIM;
  const size_t erow1 = (size_t)(wv * 32 + 16 + ccol) * D_DIM;

  f32x4 acc[2][2] = {};

  // x prefetch: xa = tile kt, xb = tile kt+1 (2-deep)
  f32x4 xa0, xa1, xb0, xb1;
  xa0 = __builtin_nontemporal_load((const f32x4*)xp);
  xa1 = __builtin_nontemporal_load((const f32x4*)xp + 1);
  xb0 = __builtin_nontemporal_load((const f32x4*)(xp + BKT));
  xb1 = __builtin_nontemporal_load((const f32x4*)(xp + BKT) + 1);

  // W prefetch: Wcur = fragments for tile kt (8 x short8), Wnxt for kt+1
  short8 Wc[8], Wn[8];
  {
    const size_t k0s0 = (size_t)gB * 8;
    const size_t k0s1 = 32 + (size_t)gB * 8;
    Wc[0] = *(const short8*)(wh + erow0 + k0s0);
    Wc[1] = *(const short8*)(wh + erow1 + k0s0);
    Wc[2] = *(const short8*)(wl + erow0 + k0s0);
    Wc[3] = *(const short8*)(wl + erow1 + k0s0);
    Wc[4] = *(const short8*)(wh + erow0 + k0s1);
    Wc[5] = *(const short8*)(wh + erow1 + k0s1);
    Wc[6] = *(const short8*)(wl + erow0 + k0s1);
    Wc[7] = *(const short8*)(wl + erow1 + k0s1);
  }

  #pragma unroll 2
  for (int kt = 0; kt < NIT; ++kt) {
    // 1) issue W prefetch for kt+1
    if (kt + 1 < NIT) {
      const size_t kb = (size_t)(kt + 1) * BKT + (size_t)gB * 8;
      Wn[0] = *(const short8*)(wh + erow0 + kb);
      Wn[1] = *(const short8*)(wh + erow1 + kb);
      Wn[2] = *(const short8*)(wl + erow0 + kb);
      Wn[3] = *(const short8*)(wl + erow1 + kb);
      Wn[4] = *(const short8*)(wh + erow0 + kb + 32);
      Wn[5] = *(const short8*)(wh + erow1 + kb + 32);
      Wn[6] = *(const short8*)(wl + erow0 + kb + 32);
      Wn[7] = *(const short8*)(wl + erow1 + kb + 32);
    }

    // 2) convert xa (tile kt) -> bf16 h/l, write LDS buf[kt&1]
    float xf[8] = {xa0[0], xa0[1], xa0[2], xa0[3], xa1[0], xa1[1], xa1[2], xa1[3]};
    uint32_t hpk[4], lpk[4];
    #pragma unroll
    for (int j = 0; j < 4; ++j) {
      uint32_t h0 = bf16_rne(xf[2*j]), h1 = bf16_rne(xf[2*j+1]);
      float h0f = __builtin_bit_cast(float, h0 << 16);
      float h1f = __builtin_bit_cast(float, h1 << 16);
      uint32_t l0 = bf16_rne(xf[2*j] - h0f), l1 = bf16_rne(xf[2*j+1] - h1f);
      hpk[j] = h0 | (h1 << 16);
      lpk[j] = l0 | (l1 << 16);
    }
    uint8_t* buf = smem + (kt & 1) * 8192;
    *(uint4*)(buf + wa_h) = make_uint4(hpk[0], hpk[1], hpk[2], hpk[3]);
    *(uint4*)(buf + wa_l) = make_uint4(lpk[0], lpk[1], lpk[2], lpk[3]);

    // 3) slide x pipeline: xa <- xb, issue xb <- tile kt+2
    xa0 = xb0; xa1 = xb1;
    if (kt + 2 < NIT) {
      const f32x4* np = (const f32x4*)(xp + (size_t)(kt + 2) * BKT);
      xb0 = __builtin_nontemporal_load(np);
      xb1 = __builtin_nontemporal_load(np + 1);
    }

    // 4) LDS writes visible, then barrier (x/W prefetches stay in flight)
    asm volatile("s_waitcnt lgkmcnt(0)" ::: "memory");
    __builtin_amdgcn_s_barrier();

    // 5) MFMA tile kt from Wc regs + LDS fragments
    #pragma unroll
    for (int s = 0; s < 2; ++s) {
      const int pr = p_r0 ^ s;
      const short8 bh0 = Wc[s * 4 + 0], bh1 = Wc[s * 4 + 1];
      const short8 bl0 = Wc[s * 4 + 2], bl1 = Wc[s * 4 + 3];
      #pragma unroll
      for (int rg = 0; rg < 2; ++rg) {
        const uint8_t* fb = buf + (s * 4 + rg * 2) * 1024 + pr * 16;
        short8 ah = *(const short8*)fb;
        short8 al = *(const short8*)(fb + 1024);
        acc[rg][0] = __builtin_amdgcn_mfma_f32_16x16x32_bf16(ah, bh0, acc[rg][0], 0, 0, 0);
        acc[rg][0] = __builtin_amdgcn_mfma_f32_16x16x32_bf16(al, bh0, acc[rg][0], 0, 0, 0);
        acc[rg][0] = __builtin_amdgcn_mfma_f32_16x16x32_bf16(ah, bl0, acc[rg][0], 0, 0, 0);
        acc[rg][1] = __builtin_amdgcn_mfma_f32_16x16x32_bf16(ah, bh1, acc[rg][1], 0, 0, 0);
        acc[rg][1] = __builtin_amdgcn_mfma_f32_16x16x32_bf16(al, bh1, acc[rg][1], 0, 0, 0);
        acc[rg][1] = __builtin_amdgcn_mfma_f32_16x16x32_bf16(ah, bl1, acc[rg][1], 0, 0, 0);
      }
    }

    // 6) slide W pipeline
    #pragma unroll
    for (int q = 0; q < 8; ++q) Wc[q] = Wn[q];
  }

  // ---- epilogue: logits -> LDS [32][128] ----
  float b0 = bias[wv * 32 + ccol];
  float b1 = bias[wv * 32 + 16 + ccol];
  __syncthreads();
  #pragma unroll
  for (int rg = 0; rg < 2; ++rg)
    #pragma unroll
    for (int ef = 0; ef < 2; ++ef)
      #pragma unroll
      for (int i = 0; i < 4; ++i) {
        int row = rg * 16 + ggr * 4 + i;
        int e = wv * 32 + ef * 16 + ccol;
        Ld[row * 128 + e] = acc[rg][ef][i] + (ef ? b1 : b0);
      }
  __syncthreads();

  // ---- top-3 per row: 8 threads/row, 16 logits each, then shfl merge ----
  {
    const int row = t >> 3, part = t & 7;
    float l1 = -3e38f, l2 = -3e38f, l3 = -3e38f;
    int   i1 = -1, i2 = -1, i3 = -1;
    auto ins = [&](float v, int e) {
      if (v > l1 || (v == l1 && e < i1)) { l3=l2; i3=i2; l2=l1; i2=i1; l1=v; i1=e; }
      else if (v > l2 || (v == l2 && e < i2)) { l3=l2; i3=i2; l2=v; i2=e; }
      else if (v > l3 || (v == l3 && e < i3)) { l3=v; i3=e; }
    };
    #pragma unroll
    for (int jj = 0; jj < 4; ++jj) {
      int j = (jj + t) & 3;
      const float* pp = Ld + row * 128 + part * 16 + j * 4;
      f32x4 v = *(const f32x4*)pp;
      int eb = part * 16 + j * 4;
      ins(v[0], eb); ins(v[1], eb + 1); ins(v[2], eb + 2); ins(v[3], eb + 3);
    }
    #pragma unroll
    for (int m = 1; m <= 4; m <<= 1) {
      float a1 = __shfl_xor(l1, m), a2 = __shfl_xor(l2, m), a3 = __shfl_xor(l3, m);
      int   b1i = __shfl_xor(i1, m), b2i = __shfl_xor(i2, m), b3i = __shfl_xor(i3, m);
      ins(a1, b1i); ins(a2, b2i); ins(a3, b3i);
    }
    if (part == 0) {
      int grow = row0 + row;
      int fl = ((l1 - l2) < TAU) || ((l2 - l3) < TAU);
      flags[grow] = fl;
      out[(size_t)grow * 2 + 0] = 1.f / (1.f + __expf(-l1));
      out[(size_t)grow * 2 + 1] = 1.f / (1.f + __expf(-l2));
      out[(size_t)N_ROWS * 2 + (size_t)grow * 2 + 0] = (float)i1;
      out[(size_t)N_ROWS * 2 + (size_t)grow * 2 + 1] = (float)i2;
    }
  }
}

// ---------------- kernel 2: exact f64 fixup for flagged rows (parallel) ----------------
__global__ __launch_bounds__(1024) void k2_fix(
    const float* __restrict__ x, const float* __restrict__ W,
    const float* __restrict__ bias, const int* __restrict__ flags,
    float* __restrict__ out)
{
  __shared__ double lgs[E_EXP];
  const int t    = threadIdx.x;        // 1024 threads = 16 waves
  const int wvi  = t >> 6, lane = t & 63;
  const int e    = wvi * 8 + (lane >> 3);  // 16 waves x 8 experts = 128
  const int sub  = lane & 7;               // 8 lanes per expert, coalesced 128B
  const int rbase = blockIdx.x * 8;

  for (int rr = 0; rr < 8; ++rr) {
    const int row = rbase + rr;
    if (!flags[row]) continue;
    const float* xr = x + (size_t)row * D_DIM;
    const float* wr = W + (size_t)e * D_DIM;
    double a0 = 0.0, a1 = 0.0, a2 = 0.0, a3 = 0.0;
    for (int j = 0; j < 128; ++j) {      // chunk c = j*8+sub, floats [c*4, c*4+4)
      const int c4 = (j * 8 + sub) * 4;
      f32x4 xv = *(const f32x4*)(xr + c4);
      f32x4 wvv = *(const f32x4*)(wr + c4);
      a0 += (double)xv[0] * wvv[0];
      a1 += (double)xv[1] * wvv[1];
      a2 += (double)xv[2] * wvv[2];
      a3 += (double)xv[3] * wvv[3];
    }
    double acc = (a0 + a1) + (a2 + a3);
    #pragma unroll
    for (int m = 1; m <= 4; m <<= 1) acc += __shfl_xor(acc, m);
    if (sub == 0) lgs[e] = acc + (double)bias[e];
    __syncthreads();
    if (t == 0) {
      double l1 = -1e300, l2 = -1e300; int i1 = -1, i2 = -1;
      for (int ee = 0; ee < E_EXP; ++ee) {
        double v = lgs[ee];
        if (v > l1) { l2 = l1; i2 = i1; l1 = v; i1 = ee; }
        else if (v > l2) { l2 = v; i2 = ee; }
      }
      out[(size_t)row * 2 + 0] = (float)(1.0 / (1.0 + exp(-l1)));
      out[(size_t)row * 2 + 1] = (float)(1.0 / (1.0 + exp(-l2)));
      out[(size_t)N_ROWS * 2 + (size_t)row * 2 + 0] = (float)i1;
      out[(size_t)N_ROWS * 2 + (size_t)row * 2 + 1] = (float)i2;
    }
    __syncthreads();
  }
}

extern "C" void kernel_launch(void* const* d_in, const int* in_sizes, int n_in,
                              void* d_out, int out_size, void* d_ws, size_t ws_size,
                              hipStream_t stream) {
  const float* x  = (const float*)d_in[0];
  const float* Wm = (const float*)d_in[1];
  const float* b  = (const float*)d_in[2];
  float* out = (float*)d_out;

  uint16_t* wh = (uint16_t*)d_ws;                          // 1 MiB
  uint16_t* wl = wh + (size_t)E_EXP * D_DIM;               // 1 MiB
  int* flags = (int*)((uint8_t*)d_ws + 2u * 1024 * 1024);  // 64 KiB

  k0_split<<<dim3((E_EXP * D_DIM) / 1024), dim3(256), 0, stream>>>(Wm, wh, wl);
  k1_main<<<dim3(N_ROWS / BM), dim3(256), 0, stream>>>(x, wh, wl, b, out, flags);
  k2_fix<<<dim3(N_ROWS / 8), dim3(1024), 0, stream>>>(x, Wm, b, flags, out);
}

// Round 6
// 229.640 us; speedup vs baseline: 2.3315x; 1.0207x over previous
//
#include <hip/hip_runtime.h>
#include <stdint.h>
#include <math.h>

#define N_ROWS 16384
#define D_DIM  4096
#define E_EXP  128
#define BM     32
#define BKR    128              // k per round
#define NR     (D_DIM / BKR)    // 32 rounds
#define TAU    2.5e-4f

typedef short  short8 __attribute__((ext_vector_type(8)));
typedef float  f32x4  __attribute__((ext_vector_type(4)));

__device__ __forceinline__ uint32_t bf16_rne(float f) {
  uint32_t u = __builtin_bit_cast(uint32_t, f);
  return (u + 0x7fffu + ((u >> 16) & 1u)) >> 16;
}

// ---------------- kernel 0: split W into bf16 hi/lo ----------------
__global__ __launch_bounds__(256) void k0_split(const float* __restrict__ W,
                                                uint16_t* __restrict__ wh,
                                                uint16_t* __restrict__ wl) {
  int i = (blockIdx.x * 256 + threadIdx.x) * 4;
  f32x4 w = *(const f32x4*)(W + i);
  uint32_t h[4], l[4];
  #pragma unroll
  for (int j = 0; j < 4; ++j) {
    h[j] = bf16_rne(w[j]);
    float hf = __builtin_bit_cast(float, h[j] << 16);
    l[j] = bf16_rne(w[j] - hf);
  }
  *(uint2*)(wh + i) = make_uint2(h[0] | (h[1] << 16), h[2] | (h[3] << 16));
  *(uint2*)(wl + i) = make_uint2(l[0] | (l[1] << 16), l[2] | (l[3] << 16));
}

// ---------------- kernel 1: split-bf16 MFMA GEMM + top3 + flags ----------------
// 512 threads = 8 waves; BM=32 rows/block; each wave owns 16 experts.
__global__ __launch_bounds__(512, 4) void k1_main(
    const float* __restrict__ x, const uint16_t* __restrict__ wh,
    const uint16_t* __restrict__ wl, const float* __restrict__ bias,
    float* __restrict__ out, int* __restrict__ flags)
{
  // 2 x 16KB staging buffers; logits overlay (16KB) reuses buffer 0.
  __shared__ __align__(16) uint8_t smem[32768];
  float* Ld = (float*)smem;

  const int t    = threadIdx.x;
  const int lane = t & 63;
  const int wv   = __builtin_amdgcn_readfirstlane(t >> 6);  // 0..7 -> experts [wv*16, wv*16+16)
  const int row0 = blockIdx.x * BM;

  // ---- X staging map: thread t loads x[row0 + (t>>4)][r*128 + (t&15)*8 ..+7]
  const int srow = t >> 4;        // 0..31
  const int skg  = t & 15;        // k-group of 8 within 128
  const float* xp = x + (size_t)(row0 + srow) * D_DIM + skg * 8;

  // ---- LDS write map (fragment blocks of 1KB: fb = s*4 + rg*2 + d) ----
  const int s_w = skg >> 2, gg_w = skg & 3, rr_w = srow & 15, rg_w = srow >> 4;
  const int p_w  = gg_w * 16 + (rr_w ^ (gg_w << 1) ^ s_w);
  const int wa_h = (s_w * 4 + rg_w * 2 + 0) * 1024 + p_w * 16;
  const int wa_l = wa_h + 1024;

  // ---- LDS read map ----
  const int ggr = lane >> 4, rrr = lane & 15;
  const int p_r0 = ggr * 16 + (rrr ^ (ggr << 1));   // step s: slot = p_r0 ^ s

  // ---- B (W) fragment map: lane holds W[wv*16+(lane&15)][k0+(lane>>4)*8 ..+7]
  const int ccol = lane & 15, gB = lane >> 4;
  const size_t erow = (size_t)(wv * 16 + ccol) * D_DIM;

  f32x4 acc[2] = {};

  // x prefetch 3-deep: xa = round r, xb = r+1, xc = r+2
  f32x4 xa0, xa1, xb0, xb1, xc0, xc1;
  xa0 = *((const f32x4*)xp + 0); xa1 = *((const f32x4*)xp + 1);
  xb0 = *((const f32x4*)(xp + BKR) + 0); xb1 = *((const f32x4*)(xp + BKR) + 1);
  xc0 = *((const f32x4*)(xp + 2 * BKR) + 0); xc1 = *((const f32x4*)(xp + 2 * BKR) + 1);

  // W prefetch: Wc = round r fragments (s*2+d), Wn = round r+1
  short8 Wc[8], Wn[8];
  #pragma unroll
  for (int s = 0; s < 4; ++s) {
    Wc[s * 2 + 0] = *(const short8*)(wh + erow + s * 32 + gB * 8);
    Wc[s * 2 + 1] = *(const short8*)(wl + erow + s * 32 + gB * 8);
  }

  #pragma unroll 2
  for (int r = 0; r < NR; ++r) {
    // 1) issue W prefetch for round r+1 (consumed next round; full-round slack)
    if (r + 1 < NR) {
      const size_t kb = (size_t)(r + 1) * BKR + (size_t)gB * 8;
      #pragma unroll
      for (int s = 0; s < 4; ++s) {
        Wn[s * 2 + 0] = *(const short8*)(wh + erow + kb + s * 32);
        Wn[s * 2 + 1] = *(const short8*)(wl + erow + kb + s * 32);
      }
    }

    // 2) convert xa -> bf16 h/l, write LDS buf[r&1]
    float xf[8] = {xa0[0], xa0[1], xa0[2], xa0[3], xa1[0], xa1[1], xa1[2], xa1[3]};
    uint32_t hpk[4], lpk[4];
    #pragma unroll
    for (int j = 0; j < 4; ++j) {
      uint32_t h0 = bf16_rne(xf[2*j]), h1 = bf16_rne(xf[2*j+1]);
      float h0f = __builtin_bit_cast(float, h0 << 16);
      float h1f = __builtin_bit_cast(float, h1 << 16);
      uint32_t l0 = bf16_rne(xf[2*j] - h0f), l1 = bf16_rne(xf[2*j+1] - h1f);
      hpk[j] = h0 | (h1 << 16);
      lpk[j] = l0 | (l1 << 16);
    }
    uint8_t* buf = smem + (r & 1) * 16384;
    *(uint4*)(buf + wa_h) = make_uint4(hpk[0], hpk[1], hpk[2], hpk[3]);
    *(uint4*)(buf + wa_l) = make_uint4(lpk[0], lpk[1], lpk[2], lpk[3]);

    // 3) rotate x pipeline; issue load for round r+3
    xa0 = xb0; xa1 = xb1; xb0 = xc0; xb1 = xc1;
    if (r + 3 < NR) {
      const f32x4* np = (const f32x4*)(xp + (size_t)(r + 3) * BKR);
      xc0 = np[0]; xc1 = np[1];
    }

    // 4) make LDS writes visible; barrier (global prefetches stay in flight)
    asm volatile("s_waitcnt lgkmcnt(0)" ::: "memory");
    __builtin_amdgcn_s_barrier();

    // 5) MFMA round r: 4 k-steps x 2 row-groups x {hh, lh, hl}
    #pragma unroll
    for (int s = 0; s < 4; ++s) {
      const int pr = p_r0 ^ s;
      const short8 bh = Wc[s * 2 + 0], bl = Wc[s * 2 + 1];
      #pragma unroll
      for (int rg = 0; rg < 2; ++rg) {
        const uint8_t* fb = buf + (s * 4 + rg * 2) * 1024 + pr * 16;
        short8 ah = *(const short8*)fb;
        short8 al = *(const short8*)(fb + 1024);
        acc[rg] = __builtin_amdgcn_mfma_f32_16x16x32_bf16(ah, bh, acc[rg], 0, 0, 0);
        acc[rg] = __builtin_amdgcn_mfma_f32_16x16x32_bf16(al, bh, acc[rg], 0, 0, 0);
        acc[rg] = __builtin_amdgcn_mfma_f32_16x16x32_bf16(ah, bl, acc[rg], 0, 0, 0);
      }
    }

    // 6) rotate W pipeline
    #pragma unroll
    for (int q = 0; q < 8; ++q) Wc[q] = Wn[q];
  }

  // ---- epilogue: logits -> LDS [32][128] ----
  float b0 = bias[wv * 16 + ccol];
  __syncthreads();
  #pragma unroll
  for (int rg = 0; rg < 2; ++rg)
    #pragma unroll
    for (int i = 0; i < 4; ++i) {
      int row = rg * 16 + ggr * 4 + i;
      int e = wv * 16 + ccol;
      Ld[row * 128 + e] = acc[rg][i] + b0;
    }
  __syncthreads();

  // ---- top-3 per row: 16 threads/row, 8 logits each, shfl merge ----
  {
    const int row = t >> 4, part = t & 15;
    float l1 = -3e38f, l2 = -3e38f, l3 = -3e38f;
    int   i1 = -1, i2 = -1, i3 = -1;
    auto ins = [&](float v, int e) {
      if (v > l1 || (v == l1 && e < i1)) { l3=l2; i3=i2; l2=l1; i2=i1; l1=v; i1=e; }
      else if (v > l2 || (v == l2 && e < i2)) { l3=l2; i3=i2; l2=v; i2=e; }
      else if (v > l3 || (v == l3 && e < i3)) { l3=v; i3=e; }
    };
    #pragma unroll
    for (int j = 0; j < 2; ++j) {
      const float* pp = Ld + row * 128 + part * 8 + j * 4;
      f32x4 v = *(const f32x4*)pp;
      int eb = part * 8 + j * 4;
      ins(v[0], eb); ins(v[1], eb + 1); ins(v[2], eb + 2); ins(v[3], eb + 3);
    }
    #pragma unroll
    for (int m = 1; m <= 8; m <<= 1) {
      float a1 = __shfl_xor(l1, m), a2 = __shfl_xor(l2, m), a3 = __shfl_xor(l3, m);
      int   b1i = __shfl_xor(i1, m), b2i = __shfl_xor(i2, m), b3i = __shfl_xor(i3, m);
      ins(a1, b1i); ins(a2, b2i); ins(a3, b3i);
    }
    if (part == 0) {
      int grow = row0 + row;
      int fl = ((l1 - l2) < TAU) || ((l2 - l3) < TAU);
      flags[grow] = fl;
      out[(size_t)grow * 2 + 0] = 1.f / (1.f + __expf(-l1));
      out[(size_t)grow * 2 + 1] = 1.f / (1.f + __expf(-l2));
      out[(size_t)N_ROWS * 2 + (size_t)grow * 2 + 0] = (float)i1;
      out[(size_t)N_ROWS * 2 + (size_t)grow * 2 + 1] = (float)i2;
    }
  }
}

// ---------------- kernel 2: exact f64 fixup for flagged rows (parallel) ----------------
__global__ __launch_bounds__(1024) void k2_fix(
    const float* __restrict__ x, const float* __restrict__ W,
    const float* __restrict__ bias, const int* __restrict__ flags,
    float* __restrict__ out)
{
  __shared__ double lgs[E_EXP];
  const int t    = threadIdx.x;        // 1024 threads = 16 waves
  const int wvi  = t >> 6, lane = t & 63;
  const int e    = wvi * 8 + (lane >> 3);  // 16 waves x 8 experts = 128
  const int sub  = lane & 7;               // 8 lanes per expert, coalesced
  const int rbase = blockIdx.x * 8;

  for (int rr = 0; rr < 8; ++rr) {
    const int row = rbase + rr;
    if (!flags[row]) continue;
    const float* xr = x + (size_t)row * D_DIM;
    const float* wr = W + (size_t)e * D_DIM;
    double a0 = 0.0, a1 = 0.0, a2 = 0.0, a3 = 0.0;
    for (int j = 0; j < 128; ++j) {
      const int c4 = (j * 8 + sub) * 4;
      f32x4 xv = *(const f32x4*)(xr + c4);
      f32x4 wvv = *(const f32x4*)(wr + c4);
      a0 += (double)xv[0] * wvv[0];
      a1 += (double)xv[1] * wvv[1];
      a2 += (double)xv[2] * wvv[2];
      a3 += (double)xv[3] * wvv[3];
    }
    double acc = (a0 + a1) + (a2 + a3);
    #pragma unroll
    for (int m = 1; m <= 4; m <<= 1) acc += __shfl_xor(acc, m);
    if (sub == 0) lgs[e] = acc + (double)bias[e];
    __syncthreads();
    if (t == 0) {
      double l1 = -1e300, l2 = -1e300; int i1 = -1, i2 = -1;
      for (int ee = 0; ee < E_EXP; ++ee) {
        double v = lgs[ee];
        if (v > l1) { l2 = l1; i2 = i1; l1 = v; i1 = ee; }
        else if (v > l2) { l2 = v; i2 = ee; }
      }
      out[(size_t)row * 2 + 0] = (float)(1.0 / (1.0 + exp(-l1)));
      out[(size_t)row * 2 + 1] = (float)(1.0 / (1.0 + exp(-l2)));
      out[(size_t)N_ROWS * 2 + (size_t)row * 2 + 0] = (float)i1;
      out[(size_t)N_ROWS * 2 + (size_t)row * 2 + 1] = (float)i2;
    }
    __syncthreads();
  }
}

extern "C" void kernel_launch(void* const* d_in, const int* in_sizes, int n_in,
                              void* d_out, int out_size, void* d_ws, size_t ws_size,
                              hipStream_t stream) {
  const float* x  = (const float*)d_in[0];
  const float* Wm = (const float*)d_in[1];
  const float* b  = (const float*)d_in[2];
  float* out = (float*)d_out;

  uint16_t* wh = (uint16_t*)d_ws;                          // 1 MiB
  uint16_t* wl = wh + (size_t)E_EXP * D_DIM;               // 1 MiB
  int* flags = (int*)((uint8_t*)d_ws + 2u * 1024 * 1024);  // 64 KiB

  k0_split<<<dim3((E_EXP * D_DIM) / 1024), dim3(256), 0, stream>>>(Wm, wh, wl);
  k1_main<<<dim3(N_ROWS / BM), dim3(512), 0, stream>>>(x, wh, wl, b, out, flags);
  k2_fix<<<dim3(N_ROWS / 8), dim3(1024), 0, stream>>>(x, Wm, b, flags, out);
}

// Round 7
// 171.328 us; speedup vs baseline: 3.1250x; 1.3404x over previous
//
#include <hip/hip_runtime.h>
#include <stdint.h>
#include <math.h>

#define N_ROWS 16384
#define D_DIM  4096
#define E_EXP  128
#define BM     32
#define BKR    128              // k per round
#define NR     (D_DIM / BKR)    // 32 rounds
#define TAU    2.5e-4f

typedef short  short8 __attribute__((ext_vector_type(8)));
typedef float  f32x4  __attribute__((ext_vector_type(4)));

__device__ __forceinline__ uint32_t bf16_rne(float f) {
  uint32_t u = __builtin_bit_cast(uint32_t, f);
  return (u + 0x7fffu + ((u >> 16) & 1u)) >> 16;
}

// ---------------- kernel 0: split W into bf16 hi/lo, FRAGMENT-TILED ----------------
// Tiled layout: 1-KB block per (eg, kc, hl);  blk = (eg*128 + kc)*2 + hl.
// Within a block, lane l holds short8 = W[eg*16 + (l&15)][kc*32 + (l>>4)*8 .. +8] (h or l).
// k1's W fragment loads are then contiguous 1 KB per wave (coalesced).
__global__ __launch_bounds__(256) void k0_split(const float* __restrict__ W,
                                                uint16_t* __restrict__ wt) {
  const int b  = blockIdx.x;       // 256 blocks
  const int t  = threadIdx.x;      // 256 threads
  const int eg  = b >> 5;          // 0..7
  const int kcg = b & 31;
  const int kc  = kcg * 4 + (t >> 6);   // 0..127
  const int lane = t & 63;
  const int e  = eg * 16 + (lane & 15);
  const int k0 = kc * 32 + (lane >> 4) * 8;

  const float* src = W + (size_t)e * D_DIM + k0;
  f32x4 w0 = *(const f32x4*)src;
  f32x4 w1 = *(const f32x4*)(src + 4);
  float wf[8] = {w0[0], w0[1], w0[2], w0[3], w1[0], w1[1], w1[2], w1[3]};

  uint16_t h[8], l[8];
  #pragma unroll
  for (int j = 0; j < 8; ++j) {
    uint32_t hh = bf16_rne(wf[j]);
    float hf = __builtin_bit_cast(float, hh << 16);
    h[j] = (uint16_t)hh;
    l[j] = (uint16_t)bf16_rne(wf[j] - hf);
  }
  const size_t blkh = ((size_t)(eg * 128 + kc) * 2 + 0) * 512;  // elements
  const size_t blkl = ((size_t)(eg * 128 + kc) * 2 + 1) * 512;
  *(short8*)(wt + blkh + lane * 8) = *(const short8*)h;
  *(short8*)(wt + blkl + lane * 8) = *(const short8*)l;
}

// ---------------- kernel 1: split-bf16 MFMA GEMM + top3 + flags ----------------
// 512 threads = 8 waves; BM=32 rows/block; each wave owns 16 experts (eg = wave id).
__global__ __launch_bounds__(512, 4) void k1_main(
    const float* __restrict__ x, const uint16_t* __restrict__ wt,
    const float* __restrict__ bias, float* __restrict__ out, int* __restrict__ flags)
{
  // 2 x 16KB staging buffers; logits overlay (16KB) reuses buffer 0.
  __shared__ __align__(16) uint8_t smem[32768];
  float* Ld = (float*)smem;

  const int t    = threadIdx.x;
  const int lane = t & 63;
  const int wv   = __builtin_amdgcn_readfirstlane(t >> 6);  // 0..7 -> experts [wv*16, wv*16+16)
  const int row0 = blockIdx.x * BM;

  // ---- X staging map: thread t loads x[row0 + (t>>4)][r*128 + (t&15)*8 ..+7]
  const int srow = t >> 4;        // 0..31
  const int skg  = t & 15;        // k-group of 8 within 128
  const float* xp = x + (size_t)(row0 + srow) * D_DIM + skg * 8;

  // ---- LDS write map (fragment blocks of 1KB: fb = s*4 + rg*2 + d) ----
  const int s_w = skg >> 2, gg_w = skg & 3, rr_w = srow & 15, rg_w = srow >> 4;
  const int p_w  = gg_w * 16 + (rr_w ^ (gg_w << 1) ^ s_w);
  const int wa_h = (s_w * 4 + rg_w * 2 + 0) * 1024 + p_w * 16;
  const int wa_l = wa_h + 1024;

  // ---- LDS read map ----
  const int ggr = lane >> 4, rrr = lane & 15;
  const int p_r0 = ggr * 16 + (rrr ^ (ggr << 1));   // step s: slot = p_r0 ^ s

  // ---- W tiled fragment pointer: short8 index = blk*64 + lane ----
  const short8* Wt8 = (const short8*)wt;
  const int ccol = lane & 15;

  f32x4 acc[2] = {};

  // x prefetch 3-deep: xa = round r, xb = r+1, xc = r+2
  f32x4 xa0, xa1, xb0, xb1, xc0, xc1;
  xa0 = *((const f32x4*)xp + 0); xa1 = *((const f32x4*)xp + 1);
  xb0 = *((const f32x4*)(xp + BKR) + 0); xb1 = *((const f32x4*)(xp + BKR) + 1);
  xc0 = *((const f32x4*)(xp + 2 * BKR) + 0); xc1 = *((const f32x4*)(xp + 2 * BKR) + 1);

  #pragma unroll 2
  for (int r = 0; r < NR; ++r) {
    // 1) W fragments for THIS round (contiguous 1-KB wave loads; consumed
    //    after conversion + barrier => ~500 cyc slack covers L2 latency)
    short8 Wc[8];
    {
      const size_t base = ((size_t)(wv * 128 + r * 4) * 2) * 64 + lane;
      #pragma unroll
      for (int s = 0; s < 4; ++s) {
        Wc[s * 2 + 0] = Wt8[base + (size_t)(s * 2 + 0) * 64];
        Wc[s * 2 + 1] = Wt8[base + (size_t)(s * 2 + 1) * 64];
      }
    }

    // 2) convert xa -> bf16 h/l, write LDS buf[r&1]
    float xf[8] = {xa0[0], xa0[1], xa0[2], xa0[3], xa1[0], xa1[1], xa1[2], xa1[3]};
    uint32_t hpk[4], lpk[4];
    #pragma unroll
    for (int j = 0; j < 4; ++j) {
      uint32_t h0 = bf16_rne(xf[2*j]), h1 = bf16_rne(xf[2*j+1]);
      float h0f = __builtin_bit_cast(float, h0 << 16);
      float h1f = __builtin_bit_cast(float, h1 << 16);
      uint32_t l0 = bf16_rne(xf[2*j] - h0f), l1 = bf16_rne(xf[2*j+1] - h1f);
      hpk[j] = h0 | (h1 << 16);
      lpk[j] = l0 | (l1 << 16);
    }
    uint8_t* buf = smem + (r & 1) * 16384;
    *(uint4*)(buf + wa_h) = make_uint4(hpk[0], hpk[1], hpk[2], hpk[3]);
    *(uint4*)(buf + wa_l) = make_uint4(lpk[0], lpk[1], lpk[2], lpk[3]);

    // 3) rotate x pipeline; issue load for round r+3
    xa0 = xb0; xa1 = xb1; xb0 = xc0; xb1 = xc1;
    if (r + 3 < NR) {
      const f32x4* np = (const f32x4*)(xp + (size_t)(r + 3) * BKR);
      xc0 = np[0]; xc1 = np[1];
    }

    // 4) make LDS writes visible; barrier (global loads stay in flight)
    asm volatile("s_waitcnt lgkmcnt(0)" ::: "memory");
    __builtin_amdgcn_s_barrier();

    // 5) MFMA round r: 4 k-steps x 2 row-groups x {hh, lh, hl}
    #pragma unroll
    for (int s = 0; s < 4; ++s) {
      const int pr = p_r0 ^ s;
      const short8 bh = Wc[s * 2 + 0], bl = Wc[s * 2 + 1];
      #pragma unroll
      for (int rg = 0; rg < 2; ++rg) {
        const uint8_t* fb = buf + (s * 4 + rg * 2) * 1024 + pr * 16;
        short8 ah = *(const short8*)fb;
        short8 al = *(const short8*)(fb + 1024);
        acc[rg] = __builtin_amdgcn_mfma_f32_16x16x32_bf16(ah, bh, acc[rg], 0, 0, 0);
        acc[rg] = __builtin_amdgcn_mfma_f32_16x16x32_bf16(al, bh, acc[rg], 0, 0, 0);
        acc[rg] = __builtin_amdgcn_mfma_f32_16x16x32_bf16(ah, bl, acc[rg], 0, 0, 0);
      }
    }
  }

  // ---- epilogue: logits -> LDS [32][128] ----
  float b0 = bias[wv * 16 + ccol];
  __syncthreads();
  #pragma unroll
  for (int rg = 0; rg < 2; ++rg)
    #pragma unroll
    for (int i = 0; i < 4; ++i) {
      int row = rg * 16 + ggr * 4 + i;
      int e = wv * 16 + ccol;
      Ld[row * 128 + e] = acc[rg][i] + b0;
    }
  __syncthreads();

  // ---- top-3 per row: 16 threads/row, 8 logits each, shfl merge ----
  {
    const int row = t >> 4, part = t & 15;
    float l1 = -3e38f, l2 = -3e38f, l3 = -3e38f;
    int   i1 = -1, i2 = -1, i3 = -1;
    auto ins = [&](float v, int e) {
      if (v > l1 || (v == l1 && e < i1)) { l3=l2; i3=i2; l2=l1; i2=i1; l1=v; i1=e; }
      else if (v > l2 || (v == l2 && e < i2)) { l3=l2; i3=i2; l2=v; i2=e; }
      else if (v > l3 || (v == l3 && e < i3)) { l3=v; i3=e; }
    };
    #pragma unroll
    for (int j = 0; j < 2; ++j) {
      const float* pp = Ld + row * 128 + part * 8 + j * 4;
      f32x4 v = *(const f32x4*)pp;
      int eb = part * 8 + j * 4;
      ins(v[0], eb); ins(v[1], eb + 1); ins(v[2], eb + 2); ins(v[3], eb + 3);
    }
    #pragma unroll
    for (int m = 1; m <= 8; m <<= 1) {
      float a1 = __shfl_xor(l1, m), a2 = __shfl_xor(l2, m), a3 = __shfl_xor(l3, m);
      int   b1i = __shfl_xor(i1, m), b2i = __shfl_xor(i2, m), b3i = __shfl_xor(i3, m);
      ins(a1, b1i); ins(a2, b2i); ins(a3, b3i);
    }
    if (part == 0) {
      int grow = row0 + row;
      int fl = ((l1 - l2) < TAU) || ((l2 - l3) < TAU);
      flags[grow] = fl;
      out[(size_t)grow * 2 + 0] = 1.f / (1.f + __expf(-l1));
      out[(size_t)grow * 2 + 1] = 1.f / (1.f + __expf(-l2));
      out[(size_t)N_ROWS * 2 + (size_t)grow * 2 + 0] = (float)i1;
      out[(size_t)N_ROWS * 2 + (size_t)grow * 2 + 1] = (float)i2;
    }
  }
}

// ---------------- kernel 2: exact f64 fixup for flagged rows (parallel) ----------------
__global__ __launch_bounds__(1024) void k2_fix(
    const float* __restrict__ x, const float* __restrict__ W,
    const float* __restrict__ bias, const int* __restrict__ flags,
    float* __restrict__ out)
{
  __shared__ double lgs[E_EXP];
  const int t    = threadIdx.x;        // 1024 threads = 16 waves
  const int wvi  = t >> 6, lane = t & 63;
  const int e    = wvi * 8 + (lane >> 3);  // 16 waves x 8 experts = 128
  const int sub  = lane & 7;               // 8 lanes per expert, coalesced
  const int rbase = blockIdx.x * 8;

  for (int rr = 0; rr < 8; ++rr) {
    const int row = rbase + rr;
    if (!flags[row]) continue;
    const float* xr = x + (size_t)row * D_DIM;
    const float* wr = W + (size_t)e * D_DIM;
    double a0 = 0.0, a1 = 0.0, a2 = 0.0, a3 = 0.0;
    for (int j = 0; j < 128; ++j) {
      const int c4 = (j * 8 + sub) * 4;
      f32x4 xv = *(const f32x4*)(xr + c4);
      f32x4 wvv = *(const f32x4*)(wr + c4);
      a0 += (double)xv[0] * wvv[0];
      a1 += (double)xv[1] * wvv[1];
      a2 += (double)xv[2] * wvv[2];
      a3 += (double)xv[3] * wvv[3];
    }
    double acc = (a0 + a1) + (a2 + a3);
    #pragma unroll
    for (int m = 1; m <= 4; m <<= 1) acc += __shfl_xor(acc, m);
    if (sub == 0) lgs[e] = acc + (double)bias[e];
    __syncthreads();
    if (t == 0) {
      double l1 = -1e300, l2 = -1e300; int i1 = -1, i2 = -1;
      for (int ee = 0; ee < E_EXP; ++ee) {
        double v = lgs[ee];
        if (v > l1) { l2 = l1; i2 = i1; l1 = v; i1 = ee; }
        else if (v > l2) { l2 = v; i2 = ee; }
      }
      out[(size_t)row * 2 + 0] = (float)(1.0 / (1.0 + exp(-l1)));
      out[(size_t)row * 2 + 1] = (float)(1.0 / (1.0 + exp(-l2)));
      out[(size_t)N_ROWS * 2 + (size_t)row * 2 + 0] = (float)i1;
      out[(size_t)N_ROWS * 2 + (size_t)row * 2 + 1] = (float)i2;
    }
    __syncthreads();
  }
}

extern "C" void kernel_launch(void* const* d_in, const int* in_sizes, int n_in,
                              void* d_out, int out_size, void* d_ws, size_t ws_size,
                              hipStream_t stream) {
  const float* x  = (const float*)d_in[0];
  const float* Wm = (const float*)d_in[1];
  const float* b  = (const float*)d_in[2];
  float* out = (float*)d_out;

  uint16_t* wt = (uint16_t*)d_ws;                          // 2 MiB tiled W (h+l)
  int* flags = (int*)((uint8_t*)d_ws + 2u * 1024 * 1024);  // 64 KiB

  k0_split<<<dim3(256), dim3(256), 0, stream>>>(Wm, wt);
  k1_main<<<dim3(N_ROWS / BM), dim3(512), 0, stream>>>(x, wt, b, out, flags);
  k2_fix<<<dim3(N_ROWS / 8), dim3(1024), 0, stream>>>(x, Wm, b, flags, out);
}